// Round 5
// baseline (418.369 us; speedup 1.0000x reference)
//
#include <hip/hip_runtime.h>

// DenseDilatedKnnGraphDGL: B=64, C=256, N=1024, layer_idx=8 -> dilation=3, k=9, k_d=27
// out[0:589824]       = src_d (int32): rank-{0,3,..,24} neighbor index + b*N
// out[589824:1179648] = dst_d (int32): j/9
//
// R5 changes vs R4 (kill per-tile latency serialization):
//  - explicit double-buffer prefetch of B-fragments (buf[2][8]) -> 1 tile of
//    global latency always in flight (R4's 64-VGPR cap forbade any prefetch)
//  - MFMA acc chain split in two (acc0: kc0-3, acc1: kc4-7) -> half latency
//  - NRM stored permuted [b][m&15][m>>4] -> lane preloads all 16 tile-norms
//    as 4x float4 at kernel start (no per-tile scalar load)
//  - insertion depth 6 (+2 sentinel slots keeps R4's pair-merge intact)
//  - __launch_bounds__(256,3) (~170 VGPR cap)
//  - trans kernel: float4 reads, pair-packed u32 LDS (2-way-free), 16B/lane
//    coalesced writes, norms fused into phase B.

typedef __bf16 bf16x8 __attribute__((ext_vector_type(8)));
typedef float  f32x4  __attribute__((ext_vector_type(4)));
typedef unsigned int u32;

#define B_   64
#define C_   256
#define N_   1024
#define NSRC (B_ * N_ * 9)   // 589824

__device__ __forceinline__ u32 umin_(u32 a, u32 b) { return a < b ? a : b; }
__device__ __forceinline__ u32 umax_(u32 a, u32 b) { return a > b ? a : b; }

// ---------------------------------------------------------------------------
// Kernel 1: transpose + fp32->bf16 + permuted row norms.
// grid 1024 = 64 b x 16 row-chunks of 64; block 256.
// Phase A: thread handles c-pair (2 rows of X) x 4 consecutive n: two float4
//   loads, RNE->bf16, pack pairs, 4x ds_write_b32 into T[n][cpair] (stride 132).
// Phase B: thread (rr=tid>>2, p=tid&3) reads row rr quarter p (8x b128),
//   writes 128B contiguous to XT (16B/lane coalesced), accumulates bf16 norm,
//   shfl-reduces over p, p==0 writes NRM_perm[b][n&15][n>>4].
__global__ __launch_bounds__(256, 2) void trans_kernel(const float* __restrict__ X,
                                                       unsigned short* __restrict__ XT,
                                                       float* __restrict__ NRM) {
    __shared__ u32 T[64][132];
    const int tid = threadIdx.x;
    const int b   = blockIdx.x >> 4;
    const int n0  = (blockIdx.x & 15) * 64;

    // ---- Phase A ----
    const int cp  = tid >> 4;          // c-pair slot 0..15 within iteration
    const int nq  = (tid & 15) * 4;    // n offset 0..60
#pragma unroll
    for (int it = 0; it < 8; ++it) {
        const int c0 = it * 32 + cp * 2;
        const float* src = X + ((size_t)b * C_ + c0) * N_ + n0 + nq;
        float4 f0 = *(const float4*)(src);
        float4 f1 = *(const float4*)(src + N_);
        const float a0[4] = {f0.x, f0.y, f0.z, f0.w};
        const float a1[4] = {f1.x, f1.y, f1.z, f1.w};
#pragma unroll
        for (int j = 0; j < 4; ++j) {
            u32 u0 = __float_as_uint(a0[j]);
            u32 u1 = __float_as_uint(a1[j]);
            u32 b0 = (u0 + 0x7FFFu + ((u0 >> 16) & 1u)) >> 16;   // RNE to bf16
            u32 b1 = (u1 + 0x7FFFu + ((u1 >> 16) & 1u)) >> 16;
            T[nq + j][it * 16 + cp] = b0 | (b1 << 16);
        }
    }
    __syncthreads();

    // ---- Phase B ----
    const int rr = tid >> 2, p = tid & 3;
    u32 tmp[32];
#pragma unroll
    for (int j = 0; j < 8; ++j)
        *(uint4*)&tmp[4 * j] = *(const uint4*)&T[rr][p * 32 + 4 * j];

    float nsq = 0.f;
#pragma unroll
    for (int j = 0; j < 32; ++j) {
        float lo = __uint_as_float(tmp[j] << 16);
        float hi = __uint_as_float(tmp[j] & 0xFFFF0000u);
        nsq = fmaf(lo, lo, fmaf(hi, hi, nsq));
    }

    uint4* dst = (uint4*)(XT + ((size_t)b * N_ + n0 + rr) * C_ + p * 64);
#pragma unroll
    for (int j = 0; j < 8; ++j)
        dst[j] = make_uint4(tmp[4 * j], tmp[4 * j + 1], tmp[4 * j + 2], tmp[4 * j + 3]);

    nsq += __shfl_xor(nsq, 1);
    nsq += __shfl_xor(nsq, 2);
    if (p == 0) {
        const int n = n0 + rr;
        NRM[b * N_ + (n & 15) * 64 + (n >> 4)] = nsq;   // permuted layout
    }
}

// ---------------------------------------------------------------------------
// bitonic-merge of a bitonic 8-seq in regs -> ascending (phases j=4,2,1)
#define SORT8(v)                                                              \
    do {                                                                      \
        u32 mn, mx;                                                           \
        mn = umin_(v[0], v[4]); mx = umax_(v[0], v[4]); v[0] = mn; v[4] = mx; \
        mn = umin_(v[1], v[5]); mx = umax_(v[1], v[5]); v[1] = mn; v[5] = mx; \
        mn = umin_(v[2], v[6]); mx = umax_(v[2], v[6]); v[2] = mn; v[6] = mx; \
        mn = umin_(v[3], v[7]); mx = umax_(v[3], v[7]); v[3] = mn; v[7] = mx; \
        mn = umin_(v[0], v[2]); mx = umax_(v[0], v[2]); v[0] = mn; v[2] = mx; \
        mn = umin_(v[1], v[3]); mx = umax_(v[1], v[3]); v[1] = mn; v[3] = mx; \
        mn = umin_(v[4], v[6]); mx = umax_(v[4], v[6]); v[4] = mn; v[6] = mx; \
        mn = umin_(v[5], v[7]); mx = umax_(v[5], v[7]); v[5] = mn; v[7] = mx; \
        mn = umin_(v[0], v[1]); mx = umax_(v[0], v[1]); v[0] = mn; v[1] = mx; \
        mn = umin_(v[2], v[3]); mx = umax_(v[2], v[3]); v[2] = mn; v[3] = mx; \
        mn = umin_(v[4], v[5]); mx = umax_(v[4], v[5]); v[4] = mn; v[5] = mx; \
        mn = umin_(v[6], v[7]); mx = umax_(v[6], v[7]); v[6] = mn; v[7] = mx; \
    } while (0)

// Kernel 2: MFMA distances + top-k selection. grid 4096; block 256 (4 waves).
__global__ __launch_bounds__(256, 3) void knn_mfma_kernel(const unsigned short* __restrict__ XT,
                                                          const float* __restrict__ NRM,
                                                          int* __restrict__ out) {
    __shared__ u32 lists[16 * 64];   // [row_local][wave*16 + slot]

    const int tid  = threadIdx.x;
    const int lane = tid & 63;
    const int w    = tid >> 6;

    const int bi   = blockIdx.x;
    const int jj   = bi >> 3;
    const int b    = (bi & 7) + 8 * (jj >> 6);   // batch-locality swizzle (mod-8)
    const int n0   = (jj & 63) * 16;

    const int lrow = lane & 15;
    const int lk   = (lane >> 4) * 8;
    const int g    = lane >> 4;
    const bool odd = lane & 1;

    const unsigned short* xtb = XT + (size_t)b * N_ * C_;
    const int m_base = w * 256;

    // A fragments (16 queries, full K=256) in registers
    bf16x8 afr[8];
    {
        const unsigned short* ap = xtb + (n0 + lrow) * C_ + lk;
#pragma unroll
        for (int kc = 0; kc < 8; ++kc)
            afr[kc] = *(const bf16x8*)(ap + kc * 32);
    }

    // all 16 tile-norms for this lane's point rows (permuted NRM layout)
    float nrmv[16];
    {
        const float* np = NRM + b * N_ + lrow * 64 + w * 16;
#pragma unroll
        for (int i = 0; i < 4; ++i)
            *(float4*)&nrmv[4 * i] = *(const float4*)(np + 4 * i);
    }

    // per-round per-lane sorted top-6 lists (ascending)
    u32 L[4][6];
#pragma unroll
    for (int r = 0; r < 4; ++r)
#pragma unroll
        for (int i = 0; i < 6; ++i) L[r][i] = 0xFFFFFFFFu;

    // ---- software-pipelined GEMM + insertion ----
    const unsigned short* bp0 = xtb + (m_base + lrow) * C_ + lk;
    bf16x8 buf[2][8];
#pragma unroll
    for (int kc = 0; kc < 8; ++kc)
        buf[0][kc] = *(const bf16x8*)(bp0 + kc * 32);

#pragma unroll
    for (int t = 0; t < 16; ++t) {
        if (t < 15) {   // prefetch t+1 BEFORE consuming t
            const unsigned short* bpn = bp0 + (size_t)(t + 1) * 16 * C_;
#pragma unroll
            for (int kc = 0; kc < 8; ++kc)
                buf[(t + 1) & 1][kc] = *(const bf16x8*)(bpn + kc * 32);
        }
        f32x4 a0 = {0.f, 0.f, 0.f, 0.f};
        f32x4 a1 = {0.f, 0.f, 0.f, 0.f};
#pragma unroll
        for (int kc = 0; kc < 4; ++kc)
            a0 = __builtin_amdgcn_mfma_f32_16x16x32_bf16(afr[kc], buf[t & 1][kc], a0, 0, 0, 0);
#pragma unroll
        for (int kc = 4; kc < 8; ++kc)
            a1 = __builtin_amdgcn_mfma_f32_16x16x32_bf16(afr[kc], buf[t & 1][kc], a1, 0, 0, 0);

        const int m = m_base + t * 16 + lrow;
        const float nm = nrmv[t];
#pragma unroll
        for (int r = 0; r < 4; ++r) {
            float f = fmaf(-2.f, a0[r] + a1[r], nm);       // d2 minus row-const
            u32 u = __float_as_uint(f);
            u = u ^ ((u32)((int)u >> 31) | 0x80000000u);   // monotonic float->uint
            u32 cur = (u & 0xFFFFFC00u) | (u32)m;          // index in low 10 bits
#pragma unroll
            for (int i = 0; i < 6; ++i) {
                u32 lo = umin_(L[r][i], cur);
                u32 hi = umax_(L[r][i], cur);
                L[r][i] = lo; cur = hi;
            }
        }
    }

    // ---- cross-lane selection: round r -> group g's row is 4g+r.
#pragma unroll
    for (int r = 0; r < 4; ++r) {
        u32 v[8], t1[8];
#pragma unroll
        for (int i = 0; i < 6; ++i) v[i] = L[r][i];
        v[6] = 0xFFFFFFFFu; v[7] = 0xFFFFFFFFu;            // sentinel pad

        // stage 1: pair formation (lanes l, l^1) -- keep all 16
#pragma unroll
        for (int i = 0; i < 8; ++i) t1[i] = __shfl_xor(v[i], 1);
#pragma unroll
        for (int i = 0; i < 8; ++i) {
            u32 mn = umin_(v[i], t1[7 - i]);
            u32 mx = umax_(v[i], t1[7 - i]);
            v[i] = odd ? mx : mn;
        }
        SORT8(v);

        // stages: pair-vs-pair keep-16 at pair distance D = 2,4,8
#pragma unroll
        for (int s = 0; s < 3; ++s) {
            const int mask = (2 << s) | 1;   // 3, 5, 9
#pragma unroll
            for (int i = 0; i < 8; ++i) t1[i] = __shfl_xor(v[i], mask);
#pragma unroll
            for (int i = 0; i < 8; ++i) v[i] = umin_(v[i], t1[7 - i]);  // keep-16
#pragma unroll
            for (int i = 0; i < 8; ++i) t1[i] = __shfl_xor(v[i], 1);
#pragma unroll
            for (int i = 0; i < 8; ++i)
                v[i] = odd ? umax_(v[i], t1[i]) : umin_(v[i], t1[i]);
            SORT8(v);
        }

        // pair 0 of each group writes the group's sorted-16
        if ((lane & 15) < 2) {
            const int base = (4 * g + r) * 64 + w * 16 + (odd ? 8 : 0);
#pragma unroll
            for (int i = 0; i < 8; ++i) lists[base + i] = v[i];
        }
    }
    __syncthreads();

    // ---- final merge: parallel rank computation
    int* out_src = out;
    int* out_dst = out + NSRC;
    {
        const int row = tid >> 4;
        const int q   = tid & 15;
        const u32* Ls = &lists[row * 64];
        const int obase = (b * N_ + n0 + row) * 9;
#pragma unroll
        for (int jl = 0; jl < 4; ++jl) {
            const u32 val = Ls[jl * 16 + q];
            int rank = q;
#pragma unroll
            for (int jp = 0; jp < 4; ++jp) {
                if (jp == jl) continue;
                const u32* Lp = Ls + jp * 16;
                int pos = 0;
                pos += (Lp[pos + 7] < val) ? 8 : 0;
                pos += (Lp[pos + 3] < val) ? 4 : 0;
                pos += (Lp[pos + 1] < val) ? 2 : 0;
                pos += (Lp[pos]     < val) ? 1 : 0;
                rank += pos;
            }
            if (rank < 25 && (rank % 3) == 0)
                out_src[obase + rank / 3] = (b << 10) | (int)(val & 1023u);
        }
    }

    const int jbase = (b * N_ + n0) * 9;
    if (tid < 16 * 9) out_dst[jbase + tid] = (jbase + tid) / 9;
}

// ---------------------------------------------------------------------------
// Fallback (R1 kernel) if workspace is too small for XT+NRM
__global__ __launch_bounds__(256, 2) void knn_kernel(const float* __restrict__ X,
                                                     int* __restrict__ out) {
    __shared__ float smem[16 * N_];
    const int tid = threadIdx.x;
    const int b  = blockIdx.x >> 6;
    const int n0 = (blockIdx.x & 63) * 16;
    const float* __restrict__ xb = X + (size_t)b * C_ * N_;
#pragma unroll
    for (int i = 0; i < 16; ++i) {
        int f = tid + i * 256;
        int c = f >> 4, qq = f & 15;
        smem[f] = xb[c * N_ + n0 + qq];
    }
    __syncthreads();
    float acc[16][4];
#pragma unroll
    for (int q = 0; q < 16; ++q) { acc[q][0] = acc[q][1] = acc[q][2] = acc[q][3] = 0.f; }
    float nrm[4] = {0.f, 0.f, 0.f, 0.f};
    for (int c = 0; c < C_; ++c) {
        const float* __restrict__ xc = xb + c * N_;
        float bv0 = xc[tid], bv1 = xc[tid + 256], bv2 = xc[tid + 512], bv3 = xc[tid + 768];
        const float4* A4 = reinterpret_cast<const float4*>(smem + c * 16);
        float4 a0 = A4[0], a1 = A4[1], a2 = A4[2], a3 = A4[3];
        float aq[16] = {a0.x, a0.y, a0.z, a0.w, a1.x, a1.y, a1.z, a1.w,
                        a2.x, a2.y, a2.z, a2.w, a3.x, a3.y, a3.z, a3.w};
#pragma unroll
        for (int q = 0; q < 16; ++q) {
            acc[q][0] = fmaf(aq[q], bv0, acc[q][0]);
            acc[q][1] = fmaf(aq[q], bv1, acc[q][1]);
            acc[q][2] = fmaf(aq[q], bv2, acc[q][2]);
            acc[q][3] = fmaf(aq[q], bv3, acc[q][3]);
        }
        nrm[0] = fmaf(bv0, bv0, nrm[0]); nrm[1] = fmaf(bv1, bv1, nrm[1]);
        nrm[2] = fmaf(bv2, bv2, nrm[2]); nrm[3] = fmaf(bv3, bv3, nrm[3]);
    }
    __syncthreads();
#pragma unroll
    for (int q = 0; q < 16; ++q) {
        smem[q * N_ + tid]       = nrm[0] - 2.f * acc[q][0];
        smem[q * N_ + tid + 256] = nrm[1] - 2.f * acc[q][1];
        smem[q * N_ + tid + 512] = nrm[2] - 2.f * acc[q][2];
        smem[q * N_ + tid + 768] = nrm[3] - 2.f * acc[q][3];
    }
    __syncthreads();
    const int lane = tid & 63;
    const int w    = tid >> 6;
    int* out_src = out;
    int* out_dst = out + NSRC;
    for (int q = w; q < 16; q += 4) {
        float v[16];
#pragma unroll
        for (int i = 0; i < 16; ++i) v[i] = smem[q * N_ + lane + i * 64];
        float lv = v[0]; int ls = 0;
#pragma unroll
        for (int i = 1; i < 16; ++i) { if (v[i] < lv) { lv = v[i]; ls = i; } }
        int lm = lane + (ls << 6);
        const int obase = (b * N_ + n0 + q) * 9;
#pragma unroll
        for (int r = 0; r < 25; ++r) {
            float bv = lv; int bm = lm;
#pragma unroll
            for (int off = 32; off >= 1; off >>= 1) {
                float ov = __shfl_xor(bv, off);
                int   om = __shfl_xor(bm, off);
                if (ov < bv || (ov == bv && om < bm)) { bv = ov; bm = om; }
            }
            if ((r % 3) == 0 && lane == 0) out_src[obase + r / 3] = b * N_ + bm;
            if (bm == lm) {
#pragma unroll
                for (int i = 0; i < 16; ++i) { if (i == ls) v[i] = 3.4e38f; }
                lv = v[0]; ls = 0;
#pragma unroll
                for (int i = 1; i < 16; ++i) { if (v[i] < lv) { lv = v[i]; ls = i; } }
                lm = lane + (ls << 6);
            }
        }
    }
    const int jbase = (b * N_ + n0) * 9;
    if (tid < 16 * 9) out_dst[jbase + tid] = (jbase + tid) / 9;
}

extern "C" void kernel_launch(void* const* d_in, const int* in_sizes, int n_in,
                              void* d_out, int out_size, void* d_ws, size_t ws_size,
                              hipStream_t stream) {
    (void)in_sizes; (void)n_in; (void)out_size;
    const float* X = (const float*)d_in[0];
    int* out = (int*)d_out;
    const size_t xt_bytes  = (size_t)B_ * N_ * C_ * 2;   // 33,554,432
    const size_t nrm_bytes = (size_t)B_ * N_ * 4;        // 262,144
    if (ws_size >= xt_bytes + nrm_bytes) {
        unsigned short* XT = (unsigned short*)d_ws;
        float* NRM = (float*)((char*)d_ws + xt_bytes);
        trans_kernel<<<dim3(B_ * 16), dim3(256), 0, stream>>>(X, XT, NRM);
        knn_mfma_kernel<<<dim3(B_ * 64), dim3(256), 0, stream>>>(XT, NRM, out);
    } else {
        knn_kernel<<<dim3(B_ * 64), dim3(256), 0, stream>>>(X, out);
    }
}

// Round 6
// 310.407 us; speedup vs baseline: 1.3478x; 1.3478x over previous
//
#include <hip/hip_runtime.h>

// DenseDilatedKnnGraphDGL: B=64, C=256, N=1024, layer_idx=8 -> dilation=3, k=9, k_d=27
// out[0:589824]       = src_d (int32): rank-{0,3,..,24} neighbor index + b*N
// out[589824:1179648] = dst_d (int32): j/9
//
// R6 changes vs R5 (async LDS staging, m97-style):
//  - B-points staged chunk-wise (64 pts = 32KB) into LDS via global_load_lds
//    dwordx4 (no VGPR round trip -> no spill, latency decoupled). 16 chunks,
//    2 barriers/chunk, 4 blocks/CU (36KB LDS, launch_bounds(256,4)).
//  - per-row 16B column rotation baked into the STAGING global address ->
//    ds_read_b128 fragment reads are bank-uniform (unrotated = 16-way conflict).
//  - trans reverted to R4 version (R5 variant regressed) + permuted NRM
//    [lrow][w][c] so knn preloads all 16 tile-norms as 4x float4.
//  - selection (insert-6, pair-merge, rank-based final) unchanged from R4/R5.

typedef __bf16 bf16x8 __attribute__((ext_vector_type(8)));
typedef float  f32x4  __attribute__((ext_vector_type(4)));
typedef unsigned int u32;

#define B_   64
#define C_   256
#define N_   1024
#define NSRC (B_ * N_ * 9)   // 589824

__device__ __forceinline__ u32 umin_(u32 a, u32 b) { return a < b ? a : b; }
__device__ __forceinline__ u32 umax_(u32 a, u32 b) { return a > b ? a : b; }

__device__ __forceinline__ void load_lds16(const void* g, void* l) {
    __builtin_amdgcn_global_load_lds((const __attribute__((address_space(1))) void*)g,
                                     (__attribute__((address_space(3))) void*)l,
                                     16, 0, 0);
}

// ---------------------------------------------------------------------------
// Kernel 1 (R4 version + permuted NRM): transpose + fp32->bf16 + row norms.
// grid 1024 = 64 b x 16 row-chunks of 64; block 256 (4 waves).
__global__ __launch_bounds__(256, 2) void trans_kernel(const float* __restrict__ X,
                                                       unsigned short* __restrict__ XT,
                                                       float* __restrict__ NRM) {
    __shared__ u32 T[64][129];
    __shared__ float part[64][5];
    const int tid  = threadIdx.x;
    const int lane = tid & 63;
    const int w    = tid >> 6;
    const int b    = blockIdx.x >> 4;
    const int n0   = (blockIdx.x & 15) * 64;

    const float* __restrict__ xb = X + ((size_t)b * C_ + w * 64) * N_ + n0 + lane;
    float nsq = 0.f;
#pragma unroll
    for (int j = 0; j < 32; ++j) {
        float f0 = xb[(size_t)(2 * j) * N_];
        float f1 = xb[(size_t)(2 * j + 1) * N_];
        nsq = fmaf(f0, f0, fmaf(f1, f1, nsq));
        u32 u0 = __float_as_uint(f0), u1 = __float_as_uint(f1);
        u32 b0 = (u0 + 0x7FFFu + ((u0 >> 16) & 1u)) >> 16;   // RNE to bf16
        u32 b1 = (u1 + 0x7FFFu + ((u1 >> 16) & 1u)) >> 16;
        T[lane][w * 32 + j] = b0 | (b1 << 16);
    }
    part[lane][w] = nsq;
    __syncthreads();

    const int rr = tid >> 2, p = tid & 3;
    u32 tmp[32];
#pragma unroll
    for (int j = 0; j < 32; ++j) tmp[j] = T[rr][p * 32 + j];
    uint4* dst = (uint4*)(XT + ((size_t)b * N_ + n0 + rr) * C_ + p * 64);
#pragma unroll
    for (int j = 0; j < 8; ++j)
        dst[j] = make_uint4(tmp[4 * j], tmp[4 * j + 1], tmp[4 * j + 2], tmp[4 * j + 3]);

    if (tid < 64) {
        const int n = n0 + tid;
        const float s = part[tid][0] + part[tid][1] + part[tid][2] + part[tid][3];
        // permuted: [m&15][ (m>>4)&3 ][ m>>6 ]
        NRM[b * N_ + (n & 15) * 64 + ((n >> 4) & 3) * 16 + (n >> 6)] = s;
    }
}

// ---------------------------------------------------------------------------
// bitonic-merge of a bitonic 8-seq in regs -> ascending (phases j=4,2,1)
#define SORT8(v)                                                              \
    do {                                                                      \
        u32 mn, mx;                                                           \
        mn = umin_(v[0], v[4]); mx = umax_(v[0], v[4]); v[0] = mn; v[4] = mx; \
        mn = umin_(v[1], v[5]); mx = umax_(v[1], v[5]); v[1] = mn; v[5] = mx; \
        mn = umin_(v[2], v[6]); mx = umax_(v[2], v[6]); v[2] = mn; v[6] = mx; \
        mn = umin_(v[3], v[7]); mx = umax_(v[3], v[7]); v[3] = mn; v[7] = mx; \
        mn = umin_(v[0], v[2]); mx = umax_(v[0], v[2]); v[0] = mn; v[2] = mx; \
        mn = umin_(v[1], v[3]); mx = umax_(v[1], v[3]); v[1] = mn; v[3] = mx; \
        mn = umin_(v[4], v[6]); mx = umax_(v[4], v[6]); v[4] = mn; v[6] = mx; \
        mn = umin_(v[5], v[7]); mx = umax_(v[5], v[7]); v[5] = mn; v[7] = mx; \
        mn = umin_(v[0], v[1]); mx = umax_(v[0], v[1]); v[0] = mn; v[1] = mx; \
        mn = umin_(v[2], v[3]); mx = umax_(v[2], v[3]); v[2] = mn; v[3] = mx; \
        mn = umin_(v[4], v[5]); mx = umax_(v[4], v[5]); v[4] = mn; v[5] = mx; \
        mn = umin_(v[6], v[7]); mx = umax_(v[6], v[7]); v[6] = mn; v[7] = mx; \
    } while (0)

// Kernel 2: MFMA distances (LDS-staged B) + top-k selection.
// grid 4096; block 256 (4 waves); 4 blocks/CU.
__global__ __launch_bounds__(256, 4) void knn_mfma_kernel(const unsigned short* __restrict__ XT,
                                                          const float* __restrict__ NRM,
                                                          int* __restrict__ out) {
    __shared__ __align__(1024) unsigned short Bt[64 * 256];   // 32KB: 64 rows x 512B
    __shared__ u32 lists[16 * 64];                            // 4KB

    const int tid  = threadIdx.x;
    const int lane = tid & 63;
    const int w    = tid >> 6;

    const int bi   = blockIdx.x;
    const int jj   = bi >> 3;
    const int b    = (bi & 7) + 8 * (jj >> 6);   // batch-locality swizzle (mod-8)
    const int n0   = (jj & 63) * 16;

    const int lrow = lane & 15;
    const int g    = lane >> 4;
    const bool odd = lane & 1;

    const unsigned short* xtb = XT + (size_t)b * N_ * C_;

    // A fragments (16 queries, full K=256) in registers
    bf16x8 afr[8];
    {
        const unsigned short* ap = xtb + (n0 + lrow) * C_ + g * 8;
#pragma unroll
        for (int kc = 0; kc < 8; ++kc)
            afr[kc] = *(const bf16x8*)(ap + kc * 32);
    }

    // all 16 tile-norms for this lane's point rows (permuted NRM layout)
    float nrmv[16];
    {
        const float* np = NRM + b * N_ + lrow * 64 + w * 16;
#pragma unroll
        for (int i = 0; i < 4; ++i)
            *(float4*)&nrmv[4 * i] = *(const float4*)(np + 4 * i);
    }

    // per-round per-lane sorted top-6 lists (ascending)
    u32 L[4][6];
#pragma unroll
    for (int r = 0; r < 4; ++r)
#pragma unroll
        for (int i = 0; i < 6; ++i) L[r][i] = 0xFFFFFFFFu;

    // staging constants for this wave
    char* const ldsw = (char*)Bt + w * 8192;                       // 16 rows x 512B
    const char* const ldsr = (char*)Bt + w * 8192 + lrow * 512;
    const int lh   = lane >> 5;          // half-wave: row parity within instr
    const int col0 = (lane & 31) * 16;   // stored col for this lane

    for (int c = 0; c < 16; ++c) {
        // ---- stage chunk c: wave w stages its 16 rows (8KB) ----
        {
            const char* gb = (const char*)(xtb + (size_t)(c * 64 + w * 16) * C_);
#pragma unroll
            for (int i = 0; i < 8; ++i) {
                const int rt  = i * 2 + lh;                      // row-in-tile 0..15
                const int col = (col0 - rt * 16) & 511;          // inverse rotation
                load_lds16(gb + (size_t)rt * 512 + col, ldsw + i * 1024);
            }
        }
        __syncthreads();   // staged data visible (drains vmcnt)

        // ---- compute tile: rows m = c*64 + w*16 + lrow ----
        f32x4 a0 = {0.f, 0.f, 0.f, 0.f};
        f32x4 a1 = {0.f, 0.f, 0.f, 0.f};
#pragma unroll
        for (int kc = 0; kc < 8; ++kc) {
            bf16x8 bfr = *(const bf16x8*)(ldsr + ((kc * 64 + g * 16 + lrow * 16) & 511));
            if (kc & 1) a1 = __builtin_amdgcn_mfma_f32_16x16x32_bf16(afr[kc], bfr, a1, 0, 0, 0);
            else        a0 = __builtin_amdgcn_mfma_f32_16x16x32_bf16(afr[kc], bfr, a0, 0, 0, 0);
        }

        const int m = c * 64 + w * 16 + lrow;
        const float nm = nrmv[c];
#pragma unroll
        for (int r = 0; r < 4; ++r) {
            float f = fmaf(-2.f, a0[r] + a1[r], nm);       // d2 minus row-const
            u32 u = __float_as_uint(f);
            u = u ^ ((u32)((int)u >> 31) | 0x80000000u);   // monotonic float->uint
            u32 cur = (u & 0xFFFFFC00u) | (u32)m;          // index in low 10 bits
#pragma unroll
            for (int i = 0; i < 6; ++i) {
                u32 lo = umin_(L[r][i], cur);
                u32 hi = umax_(L[r][i], cur);
                L[r][i] = lo; cur = hi;
            }
        }
        __syncthreads();   // all reads done before next chunk overwrites Bt
    }

    // ---- cross-lane selection: round r -> group g's row is 4g+r ----
#pragma unroll
    for (int r = 0; r < 4; ++r) {
        u32 v[8], t1[8];
#pragma unroll
        for (int i = 0; i < 6; ++i) v[i] = L[r][i];
        v[6] = 0xFFFFFFFFu; v[7] = 0xFFFFFFFFu;            // sentinel pad

        // stage 1: pair formation (lanes l, l^1) -- keep all 16
#pragma unroll
        for (int i = 0; i < 8; ++i) t1[i] = __shfl_xor(v[i], 1);
#pragma unroll
        for (int i = 0; i < 8; ++i) {
            u32 mn = umin_(v[i], t1[7 - i]);
            u32 mx = umax_(v[i], t1[7 - i]);
            v[i] = odd ? mx : mn;
        }
        SORT8(v);

        // stages: pair-vs-pair keep-16 at pair distance D = 2,4,8
#pragma unroll
        for (int s = 0; s < 3; ++s) {
            const int mask = (2 << s) | 1;   // 3, 5, 9
#pragma unroll
            for (int i = 0; i < 8; ++i) t1[i] = __shfl_xor(v[i], mask);
#pragma unroll
            for (int i = 0; i < 8; ++i) v[i] = umin_(v[i], t1[7 - i]);  // keep-16
#pragma unroll
            for (int i = 0; i < 8; ++i) t1[i] = __shfl_xor(v[i], 1);
#pragma unroll
            for (int i = 0; i < 8; ++i)
                v[i] = odd ? umax_(v[i], t1[i]) : umin_(v[i], t1[i]);
            SORT8(v);
        }

        // pair 0 of each group writes the group's sorted-16
        if ((lane & 15) < 2) {
            const int base = (4 * g + r) * 64 + w * 16 + (odd ? 8 : 0);
#pragma unroll
            for (int i = 0; i < 8; ++i) lists[base + i] = v[i];
        }
    }
    __syncthreads();

    // ---- final merge: parallel rank computation ----
    int* out_src = out;
    int* out_dst = out + NSRC;
    {
        const int row = tid >> 4;
        const int q   = tid & 15;
        const u32* Ls = &lists[row * 64];
        const int obase = (b * N_ + n0 + row) * 9;
#pragma unroll
        for (int jl = 0; jl < 4; ++jl) {
            const u32 val = Ls[jl * 16 + q];
            int rank = q;
#pragma unroll
            for (int jp = 0; jp < 4; ++jp) {
                if (jp == jl) continue;
                const u32* Lp = Ls + jp * 16;
                int pos = 0;
                pos += (Lp[pos + 7] < val) ? 8 : 0;
                pos += (Lp[pos + 3] < val) ? 4 : 0;
                pos += (Lp[pos + 1] < val) ? 2 : 0;
                pos += (Lp[pos]     < val) ? 1 : 0;
                rank += pos;
            }
            if (rank < 25 && (rank % 3) == 0)
                out_src[obase + rank / 3] = (b << 10) | (int)(val & 1023u);
        }
    }

    const int jbase = (b * N_ + n0) * 9;
    if (tid < 16 * 9) out_dst[jbase + tid] = (jbase + tid) / 9;
}

// ---------------------------------------------------------------------------
// Fallback (R1 kernel) if workspace is too small for XT+NRM
__global__ __launch_bounds__(256, 2) void knn_kernel(const float* __restrict__ X,
                                                     int* __restrict__ out) {
    __shared__ float smem[16 * N_];
    const int tid = threadIdx.x;
    const int b  = blockIdx.x >> 6;
    const int n0 = (blockIdx.x & 63) * 16;
    const float* __restrict__ xb = X + (size_t)b * C_ * N_;
#pragma unroll
    for (int i = 0; i < 16; ++i) {
        int f = tid + i * 256;
        int c = f >> 4, qq = f & 15;
        smem[f] = xb[c * N_ + n0 + qq];
    }
    __syncthreads();
    float acc[16][4];
#pragma unroll
    for (int q = 0; q < 16; ++q) { acc[q][0] = acc[q][1] = acc[q][2] = acc[q][3] = 0.f; }
    float nrm[4] = {0.f, 0.f, 0.f, 0.f};
    for (int c = 0; c < C_; ++c) {
        const float* __restrict__ xc = xb + c * N_;
        float bv0 = xc[tid], bv1 = xc[tid + 256], bv2 = xc[tid + 512], bv3 = xc[tid + 768];
        const float4* A4 = reinterpret_cast<const float4*>(smem + c * 16);
        float4 a0 = A4[0], a1 = A4[1], a2 = A4[2], a3 = A4[3];
        float aq[16] = {a0.x, a0.y, a0.z, a0.w, a1.x, a1.y, a1.z, a1.w,
                        a2.x, a2.y, a2.z, a2.w, a3.x, a3.y, a3.z, a3.w};
#pragma unroll
        for (int q = 0; q < 16; ++q) {
            acc[q][0] = fmaf(aq[q], bv0, acc[q][0]);
            acc[q][1] = fmaf(aq[q], bv1, acc[q][1]);
            acc[q][2] = fmaf(aq[q], bv2, acc[q][2]);
            acc[q][3] = fmaf(aq[q], bv3, acc[q][3]);
        }
        nrm[0] = fmaf(bv0, bv0, nrm[0]); nrm[1] = fmaf(bv1, bv1, nrm[1]);
        nrm[2] = fmaf(bv2, bv2, nrm[2]); nrm[3] = fmaf(bv3, bv3, nrm[3]);
    }
    __syncthreads();
#pragma unroll
    for (int q = 0; q < 16; ++q) {
        smem[q * N_ + tid]       = nrm[0] - 2.f * acc[q][0];
        smem[q * N_ + tid + 256] = nrm[1] - 2.f * acc[q][1];
        smem[q * N_ + tid + 512] = nrm[2] - 2.f * acc[q][2];
        smem[q * N_ + tid + 768] = nrm[3] - 2.f * acc[q][3];
    }
    __syncthreads();
    const int lane = tid & 63;
    const int w    = tid >> 6;
    int* out_src = out;
    int* out_dst = out + NSRC;
    for (int q = w; q < 16; q += 4) {
        float v[16];
#pragma unroll
        for (int i = 0; i < 16; ++i) v[i] = smem[q * N_ + lane + i * 64];
        float lv = v[0]; int ls = 0;
#pragma unroll
        for (int i = 1; i < 16; ++i) { if (v[i] < lv) { lv = v[i]; ls = i; } }
        int lm = lane + (ls << 6);
        const int obase = (b * N_ + n0 + q) * 9;
#pragma unroll
        for (int r = 0; r < 25; ++r) {
            float bv = lv; int bm = lm;
#pragma unroll
            for (int off = 32; off >= 1; off >>= 1) {
                float ov = __shfl_xor(bv, off);
                int   om = __shfl_xor(bm, off);
                if (ov < bv || (ov == bv && om < bm)) { bv = ov; bm = om; }
            }
            if ((r % 3) == 0 && lane == 0) out_src[obase + r / 3] = b * N_ + bm;
            if (bm == lm) {
#pragma unroll
                for (int i = 0; i < 16; ++i) { if (i == ls) v[i] = 3.4e38f; }
                lv = v[0]; ls = 0;
#pragma unroll
                for (int i = 1; i < 16; ++i) { if (v[i] < lv) { lv = v[i]; ls = i; } }
                lm = lane + (ls << 6);
            }
        }
    }
    const int jbase = (b * N_ + n0) * 9;
    if (tid < 16 * 9) out_dst[jbase + tid] = (jbase + tid) / 9;
}

extern "C" void kernel_launch(void* const* d_in, const int* in_sizes, int n_in,
                              void* d_out, int out_size, void* d_ws, size_t ws_size,
                              hipStream_t stream) {
    (void)in_sizes; (void)n_in; (void)out_size;
    const float* X = (const float*)d_in[0];
    int* out = (int*)d_out;
    const size_t xt_bytes  = (size_t)B_ * N_ * C_ * 2;   // 33,554,432
    const size_t nrm_bytes = (size_t)B_ * N_ * 4;        // 262,144
    if (ws_size >= xt_bytes + nrm_bytes) {
        unsigned short* XT = (unsigned short*)d_ws;
        float* NRM = (float*)((char*)d_ws + xt_bytes);
        trans_kernel<<<dim3(B_ * 16), dim3(256), 0, stream>>>(X, XT, NRM);
        knn_mfma_kernel<<<dim3(B_ * 64), dim3(256), 0, stream>>>(XT, NRM, out);
    } else {
        knn_kernel<<<dim3(B_ * 64), dim3(256), 0, stream>>>(X, out);
    }
}

// Round 7
// 169.132 us; speedup vs baseline: 2.4736x; 1.8353x over previous
//
#include <hip/hip_runtime.h>

// DenseDilatedKnnGraphDGL: B=64, C=256, N=1024, layer_idx=8 -> dilation=3, k=9, k_d=27
// out[0:589824]       = src_d (int32): rank-{0,3,..,24} neighbor index + b*N
// out[589824:1179648] = dst_d (int32): j/9
//
// R7: 64 queries/block (wave-private queries, block-shared staged points):
//  - 1024 blocks (= 4/CU exactly), each: 64 queries x 1024 points.
//  - per chunk: 4 waves cooperatively stage 64 rows (32KB) via global_load_lds
//    dwordx4; EVERY wave then computes 4 tiles vs all 64 rows -> 4x staging reuse.
//  - #pragma unroll 1 on chunk loop + no norm-vector preload -> reg demand ~92,
//    no scratch spill (R6 spilled 300MB via HBM).
//  - exact distributed top-32 per query row (pair keep16 -> quad merge32 ->
//    keep32 dist4 -> keep32 dist8), output ranks 0,3,..,24 straight from regs.
//  - LDS: 64B inter-instruction pad + per-row 16B rotation for bank spread.

typedef __bf16 bf16x8 __attribute__((ext_vector_type(8)));
typedef float  f32x4  __attribute__((ext_vector_type(4)));
typedef unsigned int u32;

#define B_   64
#define C_   256
#define N_   1024
#define NSRC (B_ * N_ * 9)   // 589824

#define STRIDE_I 1088        // 1024 + 64B pad between staging instructions
#define REGION_W 8704        // 8 * STRIDE_I per wave-region (16 rows)

__device__ __forceinline__ u32 umin_(u32 a, u32 b) { return a < b ? a : b; }
__device__ __forceinline__ u32 umax_(u32 a, u32 b) { return a > b ? a : b; }

__device__ __forceinline__ void load_lds16(const void* g, void* l) {
    __builtin_amdgcn_global_load_lds((const __attribute__((address_space(1))) void*)g,
                                     (__attribute__((address_space(3))) void*)l,
                                     16, 0, 0);
}

// ---------------------------------------------------------------------------
// Kernel 1: transpose + fp32->bf16 + row norms (bf16-consistent).
// grid 1024 = 64 b x 16 n-chunks of 64; block 256.
// Phase A: thread (cpl=tid>>4, s=tid&15): reads float4 from rows c0,c0+1 at
//   cols n0+4s; packs 4 u32 (c-pair x 4n); ONE uint4 write to T2[cp][4s].
// Phase B: thread (rr=tid>>2, p=tid&3): for j=0..7 gathers 4 b32 from
//   T2[j*16+4p+q][rr] (2-way free), writes uint4 to XT row rr at byte j*64+p*16
//   (64B-contiguous per 4 lanes), accumulates bf16 norm, shfl-reduce over p.
__global__ __launch_bounds__(256, 4) void trans_kernel(const float* __restrict__ X,
                                                       unsigned short* __restrict__ XT,
                                                       float* __restrict__ NRM) {
    __shared__ u32 T2[128][66];   // [c-pair][n_local], 33792 B
    const int tid = threadIdx.x;
    const int b   = blockIdx.x >> 4;
    const int n0  = (blockIdx.x & 15) * 64;

    // ---- Phase A ----
    {
        const int cpl = tid >> 4;        // 0..15
        const int s   = tid & 15;        // n quad slot
#pragma unroll
        for (int it = 0; it < 8; ++it) {
            const int c0 = it * 32 + cpl * 2;
            const float* src = X + ((size_t)b * C_ + c0) * N_ + n0 + s * 4;
            float4 f0 = *(const float4*)(src);
            float4 f1 = *(const float4*)(src + N_);
            const float a0[4] = {f0.x, f0.y, f0.z, f0.w};
            const float a1[4] = {f1.x, f1.y, f1.z, f1.w};
            u32 pk[4];
#pragma unroll
            for (int j = 0; j < 4; ++j) {
                u32 u0 = __float_as_uint(a0[j]);
                u32 u1 = __float_as_uint(a1[j]);
                u32 b0 = (u0 + 0x7FFFu + ((u0 >> 16) & 1u)) >> 16;   // RNE
                u32 b1 = (u1 + 0x7FFFu + ((u1 >> 16) & 1u)) >> 16;
                pk[j] = b0 | (b1 << 16);
            }
            *(uint4*)&T2[it * 16 + cpl][s * 4] = make_uint4(pk[0], pk[1], pk[2], pk[3]);
        }
    }
    __syncthreads();

    // ---- Phase B ----
    {
        const int rr = tid >> 2, p = tid & 3;
        unsigned short* xtrow = XT + ((size_t)b * N_ + n0 + rr) * C_;
        float nsq = 0.f;
#pragma unroll
        for (int j = 0; j < 8; ++j) {
            u32 x0 = T2[j * 16 + 4 * p + 0][rr];
            u32 x1 = T2[j * 16 + 4 * p + 1][rr];
            u32 x2 = T2[j * 16 + 4 * p + 2][rr];
            u32 x3 = T2[j * 16 + 4 * p + 3][rr];
            const u32 xs[4] = {x0, x1, x2, x3};
#pragma unroll
            for (int q = 0; q < 4; ++q) {
                float lo = __uint_as_float(xs[q] << 16);
                float hi = __uint_as_float(xs[q] & 0xFFFF0000u);
                nsq = fmaf(lo, lo, fmaf(hi, hi, nsq));
            }
            *(uint4*)((char*)xtrow + j * 64 + p * 16) = make_uint4(x0, x1, x2, x3);
        }
        nsq += __shfl_xor(nsq, 1);
        nsq += __shfl_xor(nsq, 2);
        if (p == 0) NRM[b * N_ + n0 + rr] = nsq;
    }
}

// ---------------------------------------------------------------------------
// bitonic-merge of a bitonic 8-seq in regs -> ascending (phases j=4,2,1)
#define SORT8(v)                                                              \
    do {                                                                      \
        u32 mn, mx;                                                           \
        mn = umin_(v[0], v[4]); mx = umax_(v[0], v[4]); v[0] = mn; v[4] = mx; \
        mn = umin_(v[1], v[5]); mx = umax_(v[1], v[5]); v[1] = mn; v[5] = mx; \
        mn = umin_(v[2], v[6]); mx = umax_(v[2], v[6]); v[2] = mn; v[6] = mx; \
        mn = umin_(v[3], v[7]); mx = umax_(v[3], v[7]); v[3] = mn; v[7] = mx; \
        mn = umin_(v[0], v[2]); mx = umax_(v[0], v[2]); v[0] = mn; v[2] = mx; \
        mn = umin_(v[1], v[3]); mx = umax_(v[1], v[3]); v[1] = mn; v[3] = mx; \
        mn = umin_(v[4], v[6]); mx = umax_(v[4], v[6]); v[4] = mn; v[6] = mx; \
        mn = umin_(v[5], v[7]); mx = umax_(v[5], v[7]); v[5] = mn; v[7] = mx; \
        mn = umin_(v[0], v[1]); mx = umax_(v[0], v[1]); v[0] = mn; v[1] = mx; \
        mn = umin_(v[2], v[3]); mx = umax_(v[2], v[3]); v[2] = mn; v[3] = mx; \
        mn = umin_(v[4], v[5]); mx = umax_(v[4], v[5]); v[4] = mn; v[5] = mx; \
        mn = umin_(v[6], v[7]); mx = umax_(v[6], v[7]); v[6] = mn; v[7] = mx; \
    } while (0)

// Kernel 2: MFMA distances (shared LDS staging) + exact distributed top-32.
// grid 1024 = 64 b x 16 query-chunks of 64; block 256 (4 waves); 4 blocks/CU.
__global__ __launch_bounds__(256, 4) void knn_mfma_kernel(const unsigned short* __restrict__ XT,
                                                          const float* __restrict__ NRM,
                                                          int* __restrict__ out) {
    __shared__ __align__(1024) char Bt[4 * REGION_W];   // 34816 B

    const int tid  = threadIdx.x;
    const int lane = tid & 63;
    const int w    = tid >> 6;

    const int bi = blockIdx.x;
    const int b  = (bi & 7) + 8 * (bi >> 7);     // batch-locality swizzle (mod-8)
    const int n0 = ((bi >> 3) & 15) * 64;        // query base (64 queries/block)

    const int lrow = lane & 15;
    const int g    = lane >> 4;
    const bool odd = lane & 1;
    const bool hiP = (lane >> 1) & 1;

    const unsigned short* xtb = XT + (size_t)b * N_ * C_;
    const float* nrmb = NRM + b * N_;

    // A fragments: wave w's 16 queries (rows n0 + w*16 + lrow), full K=256
    bf16x8 afr[8];
    {
        const unsigned short* ap = xtb + (n0 + w * 16 + lrow) * C_ + g * 8;
#pragma unroll
        for (int kc = 0; kc < 8; ++kc)
            afr[kc] = *(const bf16x8*)(ap + kc * 32);
    }

    // per-round per-lane sorted top-6 lists (ascending)
    u32 L[4][6];
#pragma unroll
    for (int r = 0; r < 4; ++r)
#pragma unroll
        for (int i = 0; i < 6; ++i) L[r][i] = 0xFFFFFFFFu;

    char* const ldsw = Bt + w * REGION_W;   // this wave's staging region
    const int lh   = lane >> 5;
    const int col0 = (lane & 31) * 16;

#pragma unroll 1
    for (int c = 0; c < 16; ++c) {
        // ---- stage: wave w stages rows c*64 + w*16 .. +16 (8KB) ----
        {
            const char* gb = (const char*)(xtb + (size_t)(c * 64 + w * 16) * C_);
#pragma unroll
            for (int i = 0; i < 8; ++i) {
                const int rt  = i * 2 + lh;                  // row within 16-block
                const int col = (col0 - rt * 16) & 511;      // inverse rotation
                load_lds16(gb + (size_t)rt * 512 + col, ldsw + i * STRIDE_I);
            }
        }
        __syncthreads();

        // ---- compute: 4 tiles (w*16 queries x 64 points) ----
#pragma unroll
        for (int t = 0; t < 4; ++t) {
            const char* rbase = Bt + t * REGION_W + (lrow >> 1) * STRIDE_I + (lrow & 1) * 512;
            f32x4 acc = {0.f, 0.f, 0.f, 0.f};
#pragma unroll
            for (int kc = 0; kc < 8; ++kc) {
                bf16x8 bfr = *(const bf16x8*)(rbase + ((kc * 64 + g * 16 + lrow * 16) & 511));
                acc = __builtin_amdgcn_mfma_f32_16x16x32_bf16(afr[kc], bfr, acc, 0, 0, 0);
            }
            const int m = c * 64 + t * 16 + lrow;
            const float nm = nrmb[m];
#pragma unroll
            for (int r = 0; r < 4; ++r) {
                float f = fmaf(-2.f, acc[r], nm);              // d2 minus row-const
                u32 u = __float_as_uint(f);
                u = u ^ ((u32)((int)u >> 31) | 0x80000000u);   // monotonic float->uint
                u32 cur = (u & 0xFFFFFC00u) | (u32)m;          // index in low 10 bits
#pragma unroll
                for (int i = 0; i < 6; ++i) {
                    u32 lo = umin_(L[r][i], cur);
                    u32 hi = umax_(L[r][i], cur);
                    L[r][i] = lo; cur = hi;
                }
            }
        }
        __syncthreads();
    }

    // ---- selection: exact distributed top-32 per query row (row = 4g+r) ----
    int* out_src = out;
    int* out_dst = out + NSRC;
#pragma unroll
    for (int r = 0; r < 4; ++r) {
        u32 v[8], t1[8];
#pragma unroll
        for (int i = 0; i < 6; ++i) v[i] = L[r][i];
        v[6] = 0xFFFFFFFFu; v[7] = 0xFFFFFFFFu;

        // S1: pair merge, keep all 16 (e: ranks 0-7, o: 8-15)
#pragma unroll
        for (int i = 0; i < 8; ++i) t1[i] = __shfl_xor(v[i], 1);
#pragma unroll
        for (int i = 0; i < 8; ++i) {
            u32 mn = umin_(v[i], t1[7 - i]);
            u32 mx = umax_(v[i], t1[7 - i]);
            v[i] = odd ? mx : mn;
        }
        SORT8(v);

        // S2: full merge of two pair-16s -> sorted-32 over quad
#pragma unroll
        for (int i = 0; i < 8; ++i) t1[i] = __shfl_xor(v[i], 3);
#pragma unroll
        for (int i = 0; i < 8; ++i) {
            u32 mn = umin_(v[i], t1[7 - i]);
            u32 mx = umax_(v[i], t1[7 - i]);
            v[i] = hiP ? mx : mn;
        }
#pragma unroll
        for (int i = 0; i < 8; ++i) t1[i] = __shfl_xor(v[i], 1);
#pragma unroll
        for (int i = 0; i < 8; ++i)
            v[i] = odd ? umax_(v[i], t1[i]) : umin_(v[i], t1[i]);
        SORT8(v);

        // S3 (dist 4) and S4 (dist 8): keep-32 of 64, then clean-32
#pragma unroll
        for (int s = 0; s < 2; ++s) {
            const int mask = s ? 11 : 7;   // flip {quad|octet}, pp, p
#pragma unroll
            for (int i = 0; i < 8; ++i) t1[i] = __shfl_xor(v[i], mask);
#pragma unroll
            for (int i = 0; i < 8; ++i) v[i] = umin_(v[i], t1[7 - i]);   // keep-32
            // clean: j=16 (pp), j=8 (parity), then in-lane
#pragma unroll
            for (int i = 0; i < 8; ++i) t1[i] = __shfl_xor(v[i], 2);
#pragma unroll
            for (int i = 0; i < 8; ++i)
                v[i] = hiP ? umax_(v[i], t1[i]) : umin_(v[i], t1[i]);
#pragma unroll
            for (int i = 0; i < 8; ++i) t1[i] = __shfl_xor(v[i], 1);
#pragma unroll
            for (int i = 0; i < 8; ++i)
                v[i] = odd ? umax_(v[i], t1[i]) : umin_(v[i], t1[i]);
            SORT8(v);
        }

        // output: quad 0 of each group holds sorted top-32; rank = 16*pp+8*p+i
        if ((lane & 12) == 0) {
            const int rank0 = (hiP ? 16 : 0) + (odd ? 8 : 0);
            const int obase = (b * N_ + n0 + w * 16 + 4 * g + r) * 9;
#pragma unroll
            for (int i = 0; i < 8; ++i) {
                const int rank = rank0 + i;
                if (rank < 25 && (rank % 3) == 0)
                    out_src[obase + rank / 3] = (b << 10) | (int)(v[i] & 1023u);
            }
        }
    }

    // ---- dst for this block: 64 queries * 9 = 576 ----
    const int jbase = (b * N_ + n0) * 9;
    for (int idx = tid; idx < 576; idx += 256)
        out_dst[jbase + idx] = (jbase + idx) / 9;
}

// ---------------------------------------------------------------------------
// Fallback (R1 kernel) if workspace is too small for XT+NRM
__global__ __launch_bounds__(256, 2) void knn_kernel(const float* __restrict__ X,
                                                     int* __restrict__ out) {
    __shared__ float smem[16 * N_];
    const int tid = threadIdx.x;
    const int b  = blockIdx.x >> 6;
    const int n0 = (blockIdx.x & 63) * 16;
    const float* __restrict__ xb = X + (size_t)b * C_ * N_;
#pragma unroll
    for (int i = 0; i < 16; ++i) {
        int f = tid + i * 256;
        int c = f >> 4, qq = f & 15;
        smem[f] = xb[c * N_ + n0 + qq];
    }
    __syncthreads();
    float acc[16][4];
#pragma unroll
    for (int q = 0; q < 16; ++q) { acc[q][0] = acc[q][1] = acc[q][2] = acc[q][3] = 0.f; }
    float nrm[4] = {0.f, 0.f, 0.f, 0.f};
    for (int c = 0; c < C_; ++c) {
        const float* __restrict__ xc = xb + c * N_;
        float bv0 = xc[tid], bv1 = xc[tid + 256], bv2 = xc[tid + 512], bv3 = xc[tid + 768];
        const float4* A4 = reinterpret_cast<const float4*>(smem + c * 16);
        float4 a0 = A4[0], a1 = A4[1], a2 = A4[2], a3 = A4[3];
        float aq[16] = {a0.x, a0.y, a0.z, a0.w, a1.x, a1.y, a1.z, a1.w,
                        a2.x, a2.y, a2.z, a2.w, a3.x, a3.y, a3.z, a3.w};
#pragma unroll
        for (int q = 0; q < 16; ++q) {
            acc[q][0] = fmaf(aq[q], bv0, acc[q][0]);
            acc[q][1] = fmaf(aq[q], bv1, acc[q][1]);
            acc[q][2] = fmaf(aq[q], bv2, acc[q][2]);
            acc[q][3] = fmaf(aq[q], bv3, acc[q][3]);
        }
        nrm[0] = fmaf(bv0, bv0, nrm[0]); nrm[1] = fmaf(bv1, bv1, nrm[1]);
        nrm[2] = fmaf(bv2, bv2, nrm[2]); nrm[3] = fmaf(bv3, bv3, nrm[3]);
    }
    __syncthreads();
#pragma unroll
    for (int q = 0; q < 16; ++q) {
        smem[q * N_ + tid]       = nrm[0] - 2.f * acc[q][0];
        smem[q * N_ + tid + 256] = nrm[1] - 2.f * acc[q][1];
        smem[q * N_ + tid + 512] = nrm[2] - 2.f * acc[q][2];
        smem[q * N_ + tid + 768] = nrm[3] - 2.f * acc[q][3];
    }
    __syncthreads();
    const int lane = tid & 63;
    const int w    = tid >> 6;
    int* out_src = out;
    int* out_dst = out + NSRC;
    for (int q = w; q < 16; q += 4) {
        float v[16];
#pragma unroll
        for (int i = 0; i < 16; ++i) v[i] = smem[q * N_ + lane + i * 64];
        float lv = v[0]; int ls = 0;
#pragma unroll
        for (int i = 1; i < 16; ++i) { if (v[i] < lv) { lv = v[i]; ls = i; } }
        int lm = lane + (ls << 6);
        const int obase = (b * N_ + n0 + q) * 9;
#pragma unroll
        for (int r = 0; r < 25; ++r) {
            float bv = lv; int bm = lm;
#pragma unroll
            for (int off = 32; off >= 1; off >>= 1) {
                float ov = __shfl_xor(bv, off);
                int   om = __shfl_xor(bm, off);
                if (ov < bv || (ov == bv && om < bm)) { bv = ov; bm = om; }
            }
            if ((r % 3) == 0 && lane == 0) out_src[obase + r / 3] = b * N_ + bm;
            if (bm == lm) {
#pragma unroll
                for (int i = 0; i < 16; ++i) { if (i == ls) v[i] = 3.4e38f; }
                lv = v[0]; ls = 0;
#pragma unroll
                for (int i = 1; i < 16; ++i) { if (v[i] < lv) { lv = v[i]; ls = i; } }
                lm = lane + (ls << 6);
            }
        }
    }
    const int jbase = (b * N_ + n0) * 9;
    if (tid < 16 * 9) out_dst[jbase + tid] = (jbase + tid) / 9;
}

extern "C" void kernel_launch(void* const* d_in, const int* in_sizes, int n_in,
                              void* d_out, int out_size, void* d_ws, size_t ws_size,
                              hipStream_t stream) {
    (void)in_sizes; (void)n_in; (void)out_size;
    const float* X = (const float*)d_in[0];
    int* out = (int*)d_out;
    const size_t xt_bytes  = (size_t)B_ * N_ * C_ * 2;   // 33,554,432
    const size_t nrm_bytes = (size_t)B_ * N_ * 4;        // 262,144
    if (ws_size >= xt_bytes + nrm_bytes) {
        unsigned short* XT = (unsigned short*)d_ws;
        float* NRM = (float*)((char*)d_ws + xt_bytes);
        trans_kernel<<<dim3(B_ * 16), dim3(256), 0, stream>>>(X, XT, NRM);
        knn_mfma_kernel<<<dim3(B_ * 16), dim3(256), 0, stream>>>(XT, NRM, out);
    } else {
        knn_kernel<<<dim3(B_ * 64), dim3(256), 0, stream>>>(X, out);
    }
}